// Round 1
// baseline (224.064 us; speedup 1.0000x reference)
//
#include <hip/hip_runtime.h>
#include <hip/hip_bf16.h>

// GIN conv: out = MLP((1+eps)*x + segment_sum(x[src], dst))
// N_NODES=100000, N_EDGES=1600000, NFEAT=NHID=64, NCLASS=16, fp32.
//
// Round 6: gather rework #2 — one node per WAVE (edge-parallel):
// lane = (edge slot t 0..3) x (float4 slot f 0..15). Wave processes its 4
// nodes sequentially with wave-uniform loop bounds (ceil(deg/4) subtiles),
// eliminating the ~50% masked-slot waste of the old 4-nodes-per-wave scheme
// (loop ran to max(deg of 4 nodes) ceil'd to 16). Edge indices stay in
// registers and are shared via ds_bpermute (sIdx LDS buffer removed -> no
// WAR hazard, compiler can pipeline next node's csr_src load).
// CSR build (bucket counting-sort) unchanged.

#define NFEAT 64
#define NHID 64
#define NCLASS 16

#define PCAP 6144
#define MAXBUCK 512
#define PT 512
#define PEPT 8
#define ST 1024
#define SEPT 6

// ---- k0: init bucket cursors ----
__global__ __launch_bounds__(512) void k_init(int* __restrict__ cursor, int nbuck)
{
    int t = threadIdx.x;
    if (t < nbuck) cursor[t] = t * PCAP;
}

// ---- k1: partition edges into buckets by dst>>8, packed (src<<8)|(dst&255) ----
__global__ __launch_bounds__(PT) void k_part(
    const int* __restrict__ ei, int* __restrict__ cursor,
    int* __restrict__ dsts, int n_edges, int nbuck)
{
    __shared__ int lcnt[MAXBUCK];
    __shared__ int sbase[MAXBUCK];
    int tid = threadIdx.x;
    for (int i = tid; i < nbuck; i += PT) lcnt[i] = 0;
    __syncthreads();

    int e0 = blockIdx.x * (PT * PEPT);
    int bk[PEPT], rk[PEPT], pk[PEPT];
    #pragma unroll
    for (int k = 0; k < PEPT; ++k) {
        int e = e0 + k * PT + tid;
        if (e < n_edges) {
            int src = ei[e];
            int dst = ei[n_edges + e];
            int b = dst >> 8;
            bk[k] = b;
            pk[k] = (src << 8) | (dst & 255);
            rk[k] = atomicAdd(&lcnt[b], 1);
        } else bk[k] = -1;
    }
    __syncthreads();
    for (int i = tid; i < nbuck; i += PT)
        sbase[i] = lcnt[i] ? atomicAdd(&cursor[i], lcnt[i]) : 0;
    __syncthreads();
    #pragma unroll
    for (int k = 0; k < PEPT; ++k)
        if (bk[k] >= 0) dsts[sbase[bk[k]] + rk[k]] = pk[k];
}

// ---- k2: scan bucket sizes -> bucket bases ----
__global__ __launch_bounds__(512) void k_bscan(
    const int* __restrict__ cursor, int* __restrict__ bbase,
    int* __restrict__ row_ptr, int nbuck, int n_edges, int n_nodes)
{
    __shared__ int sw[8];
    int t = threadIdx.x, lane = t & 63, wid = t >> 6;
    int v = (t < nbuck) ? (cursor[t] - t * PCAP) : 0;
    int s = v;
    #pragma unroll
    for (int off = 1; off < 64; off <<= 1) {
        int u = __shfl_up(s, off);
        if (lane >= off) s += u;
    }
    if (lane == 63) sw[wid] = s;
    __syncthreads();
    if (t == 0) { int a = 0; for (int i = 0; i < 8; ++i) { int tmp = sw[i]; sw[i] = a; a += tmp; } }
    __syncthreads();
    if (t < nbuck) bbase[t] = (s - v) + sw[wid];
    if (t == 0) row_ptr[n_nodes] = n_edges;
}

// ---- k3: per-bucket counting sort -> csr_src + row_ptr ----
__global__ __launch_bounds__(ST) void k_bsort(
    const int* __restrict__ dsts, const int* __restrict__ cursor,
    const int* __restrict__ bbase, int* __restrict__ csr_src,
    int* __restrict__ row_ptr, int n_nodes)
{
    __shared__ int cnt[256];
    __shared__ int off[256];
    int b = blockIdx.x;
    int tid = threadIdx.x, lane = tid & 63, wid = tid >> 6;
    int s = cursor[b] - b * PCAP;
    int gin = b * PCAP;
    if (tid < 256) cnt[tid] = 0;
    __syncthreads();

    int dk[SEPT], rk[SEPT], sk[SEPT];
    #pragma unroll
    for (int k = 0; k < SEPT; ++k) {
        int i = k * ST + tid;
        if (i < s) {
            int p = dsts[gin + i];
            int d = p & 255;
            dk[k] = d;
            sk[k] = p >> 8;
            rk[k] = atomicAdd(&cnt[d], 1);
        } else dk[k] = -1;
    }
    __syncthreads();
    if (wid == 0) {
        int c0 = cnt[lane * 4], c1 = cnt[lane * 4 + 1], c2 = cnt[lane * 4 + 2], c3 = cnt[lane * 4 + 3];
        int p1 = c0, p2 = p1 + c1, p3 = p2 + c2, p4 = p3 + c3;
        int ss = p4;
        #pragma unroll
        for (int o = 1; o < 64; o <<= 1) {
            int u = __shfl_up(ss, o);
            if (lane >= o) ss += u;
        }
        int base = ss - p4;
        off[lane * 4] = base; off[lane * 4 + 1] = base + p1;
        off[lane * 4 + 2] = base + p2; off[lane * 4 + 3] = base + p3;
    }
    __syncthreads();
    int bb = bbase[b];
    #pragma unroll
    for (int k = 0; k < SEPT; ++k)
        if (dk[k] >= 0) csr_src[bb + off[dk[k]] + rk[k]] = sk[k];
    int node = b * 256 + tid;
    if (tid < 256 && node < n_nodes) row_ptr[node] = bb + off[tid];
}

// ---- k4: fused gather + MLP. Gather: 1 node per wave (4 edges x 16 f4-slots).
__global__ __launch_bounds__(512) void k_gather_mlp(
    const float4* __restrict__ x4,     // [n][16]
    const int* __restrict__ row_ptr,
    const int* __restrict__ csr_src,
    const float* __restrict__ eps_p,
    const float* __restrict__ W1,
    const float* __restrict__ b1,
    const float* __restrict__ W2,
    const float* __restrict__ b2,
    float* __restrict__ out,
    int n_nodes)
{
    __shared__ float sW1[NFEAT * NHID];   // [k][j] 16 KB
    __shared__ float sW2[NHID * 17];      // [j][c] padded
    __shared__ float sb1[NHID];
    __shared__ float sb2[NCLASS];
    __shared__ float sh0[32][68];         // 32 nodes/block, padded rows
    __shared__ float sh1[32][68];

    int tid = threadIdx.x;
    for (int i = tid; i < NFEAT * NHID; i += 512) sW1[i] = W1[i];
    for (int i = tid; i < NHID * NCLASS; i += 512) sW2[(i >> 4) * 17 + (i & 15)] = W2[i];
    if (tid < NHID) sb1[tid] = b1[tid];
    if (tid < NCLASS) sb2[tid] = b2[tid];
    __syncthreads();

    float eps1 = 1.0f + eps_p[0];
    int wave = tid >> 6;
    int lane = tid & 63;
    int t = lane >> 4;        // edge slot 0..3 (gather phase)
    int f = lane & 15;        // float4 slot 0..15 (gather phase)

    for (int nb0 = blockIdx.x * 32; nb0 < n_nodes; nb0 += gridDim.x * 32) {
        // ---- gather: the wave's 4 nodes, sequential, 64-lane edge-parallel ----
        #pragma unroll
        for (int q = 0; q < 4; ++q) {
            int node = nb0 + wave * 4 + q;     // wave-uniform
            if (node >= n_nodes) continue;
            int s = row_ptr[node];             // scalar loads (uniform)
            int e = row_ptr[node + 1];
            float4 acc = make_float4(0.f, 0.f, 0.f, 0.f);
            for (int base = s; base < e; base += 64) {
                int p = base + lane;
                int myIdx = (p < e) ? csr_src[p] : -1;   // register staging
                int m = e - base; if (m > 64) m = 64;    // uniform
                int nfull = m >> 2;                      // uniform trip count
                for (int sub = 0; sub < nfull; ++sub) {
                    int idx = __builtin_amdgcn_ds_bpermute((sub * 4 + t) << 2, myIdx);
                    float4 v = x4[(size_t)idx * 16 + f];
                    acc.x += v.x; acc.y += v.y; acc.z += v.z; acc.w += v.w;
                }
                if (m & 3) {                             // tail: some t slots dead
                    int idx = __builtin_amdgcn_ds_bpermute((nfull * 4 + t) << 2, myIdx);
                    if (idx >= 0) {
                        float4 v = x4[(size_t)idx * 16 + f];
                        acc.x += v.x; acc.y += v.y; acc.z += v.z; acc.w += v.w;
                    }
                }
            }
            // reduce over the 4 edge slots (lane bits 4,5)
            acc.x += __shfl_xor(acc.x, 16); acc.y += __shfl_xor(acc.y, 16);
            acc.z += __shfl_xor(acc.z, 16); acc.w += __shfl_xor(acc.w, 16);
            acc.x += __shfl_xor(acc.x, 32); acc.y += __shfl_xor(acc.y, 32);
            acc.z += __shfl_xor(acc.z, 32); acc.w += __shfl_xor(acc.w, 32);
            if (t == 0) {
                float4 xs = x4[(size_t)node * 16 + f];
                acc.x += eps1 * xs.x; acc.y += eps1 * xs.y;
                acc.z += eps1 * xs.z; acc.w += eps1 * xs.w;
                *(float4*)&sh0[wave * 4 + q][f * 4] = acc;   // wave-local row
            }
        }
        // no barrier: sh0 rows 4w..4w+3 are written and read by wave w only

        // ---- layer1: lane j computes h1[j] for the wave's 4 nodes ----
        int r = wave * 4;
        float a0 = sb1[lane], a1 = a0, a2 = a0, a3 = a0;
        #pragma unroll
        for (int kk = 0; kk < 16; ++kk) {
            float4 h0 = *(const float4*)&sh0[r + 0][kk * 4];   // broadcast reads
            float4 h1v = *(const float4*)&sh0[r + 1][kk * 4];
            float4 h2 = *(const float4*)&sh0[r + 2][kk * 4];
            float4 h3 = *(const float4*)&sh0[r + 3][kk * 4];
            #pragma unroll
            for (int i = 0; i < 4; ++i) {
                float w = sW1[(kk * 4 + i) * NHID + lane];
                a0 += ((const float*)&h0)[i] * w;
                a1 += ((const float*)&h1v)[i] * w;
                a2 += ((const float*)&h2)[i] * w;
                a3 += ((const float*)&h3)[i] * w;
            }
        }
        sh1[r + 0][lane] = fmaxf(a0, 0.f);
        sh1[r + 1][lane] = fmaxf(a1, 0.f);
        sh1[r + 2][lane] = fmaxf(a2, 0.f);
        sh1[r + 3][lane] = fmaxf(a3, 0.f);

        // ---- layer2: lane (mq,mf) -> out[myNode][mf] ----
        int mq = lane >> 4;
        int mf = lane & 15;
        int nloc = wave * 4 + mq;
        int myNode = nb0 + nloc;
        float o = sb2[mf];
        #pragma unroll
        for (int jj = 0; jj < 16; ++jj) {
            float4 hv = *(const float4*)&sh1[nloc][jj * 4];
            o += hv.x * sW2[(jj * 4 + 0) * 17 + mf];
            o += hv.y * sW2[(jj * 4 + 1) * 17 + mf];
            o += hv.z * sW2[(jj * 4 + 2) * 17 + mf];
            o += hv.w * sW2[(jj * 4 + 3) * 17 + mf];
        }
        if (myNode < n_nodes) out[(size_t)myNode * NCLASS + mf] = o;
    }
}

extern "C" void kernel_launch(void* const* d_in, const int* in_sizes, int n_in,
                              void* d_out, int out_size, void* d_ws, size_t ws_size,
                              hipStream_t stream) {
    const float* x   = (const float*)d_in[0];
    const int*   ei  = (const int*)d_in[1];
    const float* eps = (const float*)d_in[2];
    const float* W1  = (const float*)d_in[3];
    const float* b1  = (const float*)d_in[4];
    const float* W2  = (const float*)d_in[5];
    const float* b2  = (const float*)d_in[6];
    float* out = (float*)d_out;

    int n_nodes = in_sizes[0] / NFEAT;            // 100000
    int n_edges = in_sizes[1] / 2;                // 1600000
    int nbuck = (n_nodes + 255) / 256;            // 391

    char* ws = (char*)d_ws;
    int* cursor  = (int*)ws;
    int* bbase   = (int*)(ws + 2048);
    int* dsts    = (int*)(ws + 4096);
    size_t o_rp  = 4096 + (size_t)nbuck * PCAP * 4;
    int* row_ptr = (int*)(ws + o_rp);
    int* csr_src = (int*)(ws + o_rp + 400128);

    k_init<<<1, 512, 0, stream>>>(cursor, nbuck);
    k_part<<<(n_edges + PT * PEPT - 1) / (PT * PEPT), PT, 0, stream>>>(
        ei, cursor, dsts, n_edges, nbuck);
    k_bscan<<<1, 512, 0, stream>>>(cursor, bbase, row_ptr, nbuck, n_edges, n_nodes);
    k_bsort<<<nbuck, ST, 0, stream>>>(dsts, cursor, bbase, csr_src, row_ptr, n_nodes);
    k_gather_mlp<<<(n_nodes + 31) / 32, 512, 0, stream>>>(
        (const float4*)x, row_ptr, csr_src, eps, W1, b1, W2, b2, out, n_nodes);
}

// Round 4
// 216.798 us; speedup vs baseline: 1.0335x; 1.0335x over previous
//
#include <hip/hip_runtime.h>
#include <hip/hip_bf16.h>
#include <hip/hip_fp16.h>

// GIN conv: out = MLP((1+eps)*x + segment_sum(x[src], dst))
// N_NODES=100000, N_EDGES=1600000, NFEAT=NHID=64, NCLASS=16, fp32.
//
// Round 9 = Round 7 resubmitted again (two GPU-acquisition timeouts; the
// fp16-gather kernel is still unmeasured — no data to iterate on).
// Gather = R5 structure (4 nodes/wave, 16 lanes/node, LDS-staged indices,
// fully-unrolled 16 independent guarded loads per lane = max MLP)
// + fp16 neighbor payload: x pre-converted to fp16 (k_cvt); gather reads
// 8B/lane instead of 16B, halving per-XCD compulsory L2 misses (measured
// bottleneck: 186MB FETCH ~= 8 XCDs x 25.6MB of x, miss-queue bound).
// Self term stays exact fp32. CSR build (bucket counting-sort) unchanged.

#define NFEAT 64
#define NHID 64
#define NCLASS 16

#define PCAP 6144
#define MAXBUCK 512
#define PT 512
#define PEPT 8
#define ST 1024
#define SEPT 6

// ---- k0: init bucket cursors ----
__global__ __launch_bounds__(512) void k_init(int* __restrict__ cursor, int nbuck)
{
    int t = threadIdx.x;
    if (t < nbuck) cursor[t] = t * PCAP;
}

// ---- k_cvt: x fp32 -> fp16 (for neighbor gather only) ----
__global__ __launch_bounds__(512) void k_cvt(
    const float4* __restrict__ x4, uint2* __restrict__ xh, int n4)
{
    int i = blockIdx.x * 512 + threadIdx.x;
    if (i < n4) {
        float4 v = x4[i];
        __half2 a = __floats2half2_rn(v.x, v.y);
        __half2 b = __floats2half2_rn(v.z, v.w);
        uint2 o;
        o.x = *reinterpret_cast<unsigned int*>(&a);
        o.y = *reinterpret_cast<unsigned int*>(&b);
        xh[i] = o;
    }
}

// ---- k1: partition edges into buckets by dst>>8, packed (src<<8)|(dst&255) ----
__global__ __launch_bounds__(PT) void k_part(
    const int* __restrict__ ei, int* __restrict__ cursor,
    int* __restrict__ dsts, int n_edges, int nbuck)
{
    __shared__ int lcnt[MAXBUCK];
    __shared__ int sbase[MAXBUCK];
    int tid = threadIdx.x;
    for (int i = tid; i < nbuck; i += PT) lcnt[i] = 0;
    __syncthreads();

    int e0 = blockIdx.x * (PT * PEPT);
    int bk[PEPT], rk[PEPT], pk[PEPT];
    #pragma unroll
    for (int k = 0; k < PEPT; ++k) {
        int e = e0 + k * PT + tid;
        if (e < n_edges) {
            int src = ei[e];
            int dst = ei[n_edges + e];
            int b = dst >> 8;
            bk[k] = b;
            pk[k] = (src << 8) | (dst & 255);
            rk[k] = atomicAdd(&lcnt[b], 1);
        } else bk[k] = -1;
    }
    __syncthreads();
    for (int i = tid; i < nbuck; i += PT)
        sbase[i] = lcnt[i] ? atomicAdd(&cursor[i], lcnt[i]) : 0;
    __syncthreads();
    #pragma unroll
    for (int k = 0; k < PEPT; ++k)
        if (bk[k] >= 0) dsts[sbase[bk[k]] + rk[k]] = pk[k];
}

// ---- k2: scan bucket sizes -> bucket bases ----
__global__ __launch_bounds__(512) void k_bscan(
    const int* __restrict__ cursor, int* __restrict__ bbase,
    int* __restrict__ row_ptr, int nbuck, int n_edges, int n_nodes)
{
    __shared__ int sw[8];
    int t = threadIdx.x, lane = t & 63, wid = t >> 6;
    int v = (t < nbuck) ? (cursor[t] - t * PCAP) : 0;
    int s = v;
    #pragma unroll
    for (int off = 1; off < 64; off <<= 1) {
        int u = __shfl_up(s, off);
        if (lane >= off) s += u;
    }
    if (lane == 63) sw[wid] = s;
    __syncthreads();
    if (t == 0) { int a = 0; for (int i = 0; i < 8; ++i) { int tmp = sw[i]; sw[i] = a; a += tmp; } }
    __syncthreads();
    if (t < nbuck) bbase[t] = (s - v) + sw[wid];
    if (t == 0) row_ptr[n_nodes] = n_edges;
}

// ---- k3: per-bucket counting sort -> csr_src + row_ptr ----
__global__ __launch_bounds__(ST) void k_bsort(
    const int* __restrict__ dsts, const int* __restrict__ cursor,
    const int* __restrict__ bbase, int* __restrict__ csr_src,
    int* __restrict__ row_ptr, int n_nodes)
{
    __shared__ int cnt[256];
    __shared__ int off[256];
    int b = blockIdx.x;
    int tid = threadIdx.x, lane = tid & 63, wid = tid >> 6;
    int s = cursor[b] - b * PCAP;
    int gin = b * PCAP;
    if (tid < 256) cnt[tid] = 0;
    __syncthreads();

    int dk[SEPT], rk[SEPT], sk[SEPT];
    #pragma unroll
    for (int k = 0; k < SEPT; ++k) {
        int i = k * ST + tid;
        if (i < s) {
            int p = dsts[gin + i];
            int d = p & 255;
            dk[k] = d;
            sk[k] = p >> 8;
            rk[k] = atomicAdd(&cnt[d], 1);
        } else dk[k] = -1;
    }
    __syncthreads();
    if (wid == 0) {
        int c0 = cnt[lane * 4], c1 = cnt[lane * 4 + 1], c2 = cnt[lane * 4 + 2], c3 = cnt[lane * 4 + 3];
        int p1 = c0, p2 = p1 + c1, p3 = p2 + c2, p4 = p3 + c3;
        int ss = p4;
        #pragma unroll
        for (int o = 1; o < 64; o <<= 1) {
            int u = __shfl_up(ss, o);
            if (lane >= o) ss += u;
        }
        int base = ss - p4;
        off[lane * 4] = base; off[lane * 4 + 1] = base + p1;
        off[lane * 4 + 2] = base + p2; off[lane * 4 + 3] = base + p3;
    }
    __syncthreads();
    int bb = bbase[b];
    #pragma unroll
    for (int k = 0; k < SEPT; ++k)
        if (dk[k] >= 0) csr_src[bb + off[dk[k]] + rk[k]] = sk[k];
    int node = b * 256 + tid;
    if (tid < 256 && node < n_nodes) row_ptr[node] = bb + off[tid];
}

// ---- k4: fused gather + MLP, 4 nodes per wave, fp16 neighbor loads ----
__global__ __launch_bounds__(512) void k_gather_mlp(
    const float4* __restrict__ x4,     // [n][16] fp32 (self term)
    const uint2* __restrict__ xh,      // [n][16] fp16x4 (neighbor gather)
    const int* __restrict__ row_ptr,
    const int* __restrict__ csr_src,
    const float* __restrict__ eps_p,
    const float* __restrict__ W1,
    const float* __restrict__ b1,
    const float* __restrict__ W2,
    const float* __restrict__ b2,
    float* __restrict__ out,
    int n_nodes)
{
    __shared__ float sW1[NFEAT * NHID];   // [k][j] 16 KB
    __shared__ float sW2[NHID * 17];      // [j][c] padded
    __shared__ float sb1[NHID];
    __shared__ float sb2[NCLASS];
    __shared__ float sh0[32][68];         // 32 nodes/block, padded rows
    __shared__ float sh1[32][68];
    __shared__ int   sIdx[8][64];

    int tid = threadIdx.x;
    for (int i = tid; i < NFEAT * NHID; i += 512) sW1[i] = W1[i];
    for (int i = tid; i < NHID * NCLASS; i += 512) sW2[(i >> 4) * 17 + (i & 15)] = W2[i];
    if (tid < NHID) sb1[tid] = b1[tid];
    if (tid < NCLASS) sb2[tid] = b2[tid];
    __syncthreads();

    float eps1 = 1.0f + eps_p[0];
    int wave = tid >> 6;
    int lane = tid & 63;
    int q = lane >> 4;        // node sub-index 0..3
    int f = lane & 15;        // 4-feature slot 0..15
    int nloc = wave * 4 + q;  // local node row

    for (int nb0 = blockIdx.x * 32; nb0 < n_nodes; nb0 += gridDim.x * 32) {
        int myNode = nb0 + nloc;
        bool valid = myNode < n_nodes;
        int s = 0, e = 0;
        if (valid) { s = row_ptr[myNode]; e = row_ptr[myNode + 1]; }
        int dmax = e - s;
        dmax = max(dmax, __shfl_xor(dmax, 16));
        dmax = max(dmax, __shfl_xor(dmax, 32));

        float4 acc = make_float4(0.f, 0.f, 0.f, 0.f);
        for (int base = 0; base < dmax; base += 16) {
            int p = s + base + f;                       // lane stages slot q*16+f
            sIdx[wave][lane] = (p < e) ? csr_src[p] : -1;
            // wave-lockstep LDS write->read, no barrier
            #pragma unroll
            for (int t = 0; t < 16; ++t) {
                int idx = sIdx[wave][q * 16 + t];
                if (idx >= 0) {
                    uint2 u = xh[(size_t)idx * 16 + f];
                    __half2 h0 = *reinterpret_cast<__half2*>(&u.x);
                    __half2 h1 = *reinterpret_cast<__half2*>(&u.y);
                    float2 f0 = __half22float2(h0);
                    float2 f1 = __half22float2(h1);
                    acc.x += f0.x; acc.y += f0.y;
                    acc.z += f1.x; acc.w += f1.y;
                }
            }
        }
        if (valid) {
            float4 xs = x4[(size_t)myNode * 16 + f];
            acc.x += eps1 * xs.x; acc.y += eps1 * xs.y;
            acc.z += eps1 * xs.z; acc.w += eps1 * xs.w;
        }
        *(float4*)&sh0[nloc][f * 4] = acc;

        // layer1: lane j computes h1[j] for the wave's 4 nodes
        int r = wave * 4;
        float a0 = sb1[lane], a1 = a0, a2 = a0, a3 = a0;
        #pragma unroll
        for (int kk = 0; kk < 16; ++kk) {
            float4 h0 = *(const float4*)&sh0[r + 0][kk * 4];   // broadcast reads
            float4 h1v = *(const float4*)&sh0[r + 1][kk * 4];
            float4 h2 = *(const float4*)&sh0[r + 2][kk * 4];
            float4 h3 = *(const float4*)&sh0[r + 3][kk * 4];
            #pragma unroll
            for (int i = 0; i < 4; ++i) {
                float w = sW1[(kk * 4 + i) * NHID + lane];
                a0 += ((const float*)&h0)[i] * w;
                a1 += ((const float*)&h1v)[i] * w;
                a2 += ((const float*)&h2)[i] * w;
                a3 += ((const float*)&h3)[i] * w;
            }
        }
        sh1[r + 0][lane] = fmaxf(a0, 0.f);
        sh1[r + 1][lane] = fmaxf(a1, 0.f);
        sh1[r + 2][lane] = fmaxf(a2, 0.f);
        sh1[r + 3][lane] = fmaxf(a3, 0.f);

        // layer2: lane (q,f) -> out[myNode][f]
        float o = sb2[f];
        #pragma unroll
        for (int jj = 0; jj < 16; ++jj) {
            float4 hv = *(const float4*)&sh1[nloc][jj * 4];
            o += hv.x * sW2[(jj * 4 + 0) * 17 + f];
            o += hv.y * sW2[(jj * 4 + 1) * 17 + f];
            o += hv.z * sW2[(jj * 4 + 2) * 17 + f];
            o += hv.w * sW2[(jj * 4 + 3) * 17 + f];
        }
        if (valid) out[(size_t)myNode * NCLASS + f] = o;
    }
}

extern "C" void kernel_launch(void* const* d_in, const int* in_sizes, int n_in,
                              void* d_out, int out_size, void* d_ws, size_t ws_size,
                              hipStream_t stream) {
    const float* x   = (const float*)d_in[0];
    const int*   ei  = (const int*)d_in[1];
    const float* eps = (const float*)d_in[2];
    const float* W1  = (const float*)d_in[3];
    const float* b1  = (const float*)d_in[4];
    const float* W2  = (const float*)d_in[5];
    const float* b2  = (const float*)d_in[6];
    float* out = (float*)d_out;

    int n_nodes = in_sizes[0] / NFEAT;            // 100000
    int n_edges = in_sizes[1] / 2;                // 1600000
    int nbuck = (n_nodes + 255) / 256;            // 391

    char* ws = (char*)d_ws;
    int* cursor  = (int*)ws;
    int* bbase   = (int*)(ws + 2048);
    int* dsts    = (int*)(ws + 4096);
    size_t o_rp  = 4096 + (size_t)nbuck * PCAP * 4;        // dsts end
    int* row_ptr = (int*)(ws + o_rp);
    int* csr_src = (int*)(ws + o_rp + 400128);
    size_t o_xh  = o_rp + 400128 + (size_t)n_edges * 4;    // csr end
    o_xh = (o_xh + 15) & ~(size_t)15;
    uint2* xh    = (uint2*)(ws + o_xh);                    // [n][16] fp16x4, 12.8MB

    int n4 = n_nodes * 16;
    k_init<<<1, 512, 0, stream>>>(cursor, nbuck);
    k_cvt<<<(n4 + 511) / 512, 512, 0, stream>>>((const float4*)x, xh, n4);
    k_part<<<(n_edges + PT * PEPT - 1) / (PT * PEPT), PT, 0, stream>>>(
        ei, cursor, dsts, n_edges, nbuck);
    k_bscan<<<1, 512, 0, stream>>>(cursor, bbase, row_ptr, nbuck, n_edges, n_nodes);
    k_bsort<<<nbuck, ST, 0, stream>>>(dsts, cursor, bbase, csr_src, row_ptr, n_nodes);
    k_gather_mlp<<<(n_nodes + 31) / 32, 512, 0, stream>>>(
        (const float4*)x, xh, row_ptr, csr_src, eps, W1, b1, W2, b2, out, n_nodes);
}

// Round 8
// 185.455 us; speedup vs baseline: 1.2082x; 1.1690x over previous
//
#include <hip/hip_runtime.h>
#include <hip/hip_bf16.h>
#include <hip/hip_fp16.h>

// GIN conv: out = MLP((1+eps)*x + segment_sum(x[src], dst))
// N_NODES=100000, N_EDGES=1600000, NFEAT=NHID=64, NCLASS=16, fp32.
//
// Round 13 = Round 10 resubmitted (4th acquisition timeout; unmeasured).
// R4 measured: fp16 payload halved FETCH (186->92MB) but dur only
// 117->100us => gather is REQUEST-count/latency-bound, not byte-bound.
// This kernel halves scattered requests at constant bytes: 16B uint4 loads
// (8 fp16 features/lane), 8 lanes per neighbor row, 2 edges in flight per
// 16-lane group (lane = s8 edge-parity x f8 feature-octet). Per 16-edge
// batch: 8 loads/lane instead of 16. Combine via shfl_xor(.,8).
// Grid 3125->1024 blocks (grid-stride ~3 tiles) to amortize 17KB/block
// weight staging + dispatch. CSR build unchanged.

#define NFEAT 64
#define NHID 64
#define NCLASS 16

#define PCAP 6144
#define MAXBUCK 512
#define PT 512
#define PEPT 8
#define ST 1024
#define SEPT 6

// ---- k0: init bucket cursors ----
__global__ __launch_bounds__(512) void k_init(int* __restrict__ cursor, int nbuck)
{
    int t = threadIdx.x;
    if (t < nbuck) cursor[t] = t * PCAP;
}

// ---- k_cvt: x fp32 -> fp16 (for neighbor gather only) ----
__global__ __launch_bounds__(512) void k_cvt(
    const float4* __restrict__ x4, uint2* __restrict__ xh, int n4)
{
    int i = blockIdx.x * 512 + threadIdx.x;
    if (i < n4) {
        float4 v = x4[i];
        __half2 a = __floats2half2_rn(v.x, v.y);
        __half2 b = __floats2half2_rn(v.z, v.w);
        uint2 o;
        o.x = *reinterpret_cast<unsigned int*>(&a);
        o.y = *reinterpret_cast<unsigned int*>(&b);
        xh[i] = o;
    }
}

// ---- k1: partition edges into buckets by dst>>8, packed (src<<8)|(dst&255) ----
__global__ __launch_bounds__(PT) void k_part(
    const int* __restrict__ ei, int* __restrict__ cursor,
    int* __restrict__ dsts, int n_edges, int nbuck)
{
    __shared__ int lcnt[MAXBUCK];
    __shared__ int sbase[MAXBUCK];
    int tid = threadIdx.x;
    for (int i = tid; i < nbuck; i += PT) lcnt[i] = 0;
    __syncthreads();

    int e0 = blockIdx.x * (PT * PEPT);
    int bk[PEPT], rk[PEPT], pk[PEPT];
    #pragma unroll
    for (int k = 0; k < PEPT; ++k) {
        int e = e0 + k * PT + tid;
        if (e < n_edges) {
            int src = ei[e];
            int dst = ei[n_edges + e];
            int b = dst >> 8;
            bk[k] = b;
            pk[k] = (src << 8) | (dst & 255);
            rk[k] = atomicAdd(&lcnt[b], 1);
        } else bk[k] = -1;
    }
    __syncthreads();
    for (int i = tid; i < nbuck; i += PT)
        sbase[i] = lcnt[i] ? atomicAdd(&cursor[i], lcnt[i]) : 0;
    __syncthreads();
    #pragma unroll
    for (int k = 0; k < PEPT; ++k)
        if (bk[k] >= 0) dsts[sbase[bk[k]] + rk[k]] = pk[k];
}

// ---- k2: scan bucket sizes -> bucket bases ----
__global__ __launch_bounds__(512) void k_bscan(
    const int* __restrict__ cursor, int* __restrict__ bbase,
    int* __restrict__ row_ptr, int nbuck, int n_edges, int n_nodes)
{
    __shared__ int sw[8];
    int t = threadIdx.x, lane = t & 63, wid = t >> 6;
    int v = (t < nbuck) ? (cursor[t] - t * PCAP) : 0;
    int s = v;
    #pragma unroll
    for (int off = 1; off < 64; off <<= 1) {
        int u = __shfl_up(s, off);
        if (lane >= off) s += u;
    }
    if (lane == 63) sw[wid] = s;
    __syncthreads();
    if (t == 0) { int a = 0; for (int i = 0; i < 8; ++i) { int tmp = sw[i]; sw[i] = a; a += tmp; } }
    __syncthreads();
    if (t < nbuck) bbase[t] = (s - v) + sw[wid];
    if (t == 0) row_ptr[n_nodes] = n_edges;
}

// ---- k3: per-bucket counting sort -> csr_src + row_ptr ----
__global__ __launch_bounds__(ST) void k_bsort(
    const int* __restrict__ dsts, const int* __restrict__ cursor,
    const int* __restrict__ bbase, int* __restrict__ csr_src,
    int* __restrict__ row_ptr, int n_nodes)
{
    __shared__ int cnt[256];
    __shared__ int off[256];
    int b = blockIdx.x;
    int tid = threadIdx.x, lane = tid & 63, wid = tid >> 6;
    int s = cursor[b] - b * PCAP;
    int gin = b * PCAP;
    if (tid < 256) cnt[tid] = 0;
    __syncthreads();

    int dk[SEPT], rk[SEPT], sk[SEPT];
    #pragma unroll
    for (int k = 0; k < SEPT; ++k) {
        int i = k * ST + tid;
        if (i < s) {
            int p = dsts[gin + i];
            int d = p & 255;
            dk[k] = d;
            sk[k] = p >> 8;
            rk[k] = atomicAdd(&cnt[d], 1);
        } else dk[k] = -1;
    }
    __syncthreads();
    if (wid == 0) {
        int c0 = cnt[lane * 4], c1 = cnt[lane * 4 + 1], c2 = cnt[lane * 4 + 2], c3 = cnt[lane * 4 + 3];
        int p1 = c0, p2 = p1 + c1, p3 = p2 + c2, p4 = p3 + c3;
        int ss = p4;
        #pragma unroll
        for (int o = 1; o < 64; o <<= 1) {
            int u = __shfl_up(ss, o);
            if (lane >= o) ss += u;
        }
        int base = ss - p4;
        off[lane * 4] = base; off[lane * 4 + 1] = base + p1;
        off[lane * 4 + 2] = base + p2; off[lane * 4 + 3] = base + p3;
    }
    __syncthreads();
    int bb = bbase[b];
    #pragma unroll
    for (int k = 0; k < SEPT; ++k)
        if (dk[k] >= 0) csr_src[bb + off[dk[k]] + rk[k]] = sk[k];
    int node = b * 256 + tid;
    if (tid < 256 && node < n_nodes) row_ptr[node] = bb + off[tid];
}

// ---- k4: fused gather + MLP, 4 nodes/wave, 16B fp16 loads, 2 edges in flight ----
__global__ __launch_bounds__(512) void k_gather_mlp(
    const float4* __restrict__ x4,     // [n][16] fp32 (self term)
    const uint2* __restrict__ xh,      // [n][16] fp16x4 (neighbor gather)
    const int* __restrict__ row_ptr,
    const int* __restrict__ csr_src,
    const float* __restrict__ eps_p,
    const float* __restrict__ W1,
    const float* __restrict__ b1,
    const float* __restrict__ W2,
    const float* __restrict__ b2,
    float* __restrict__ out,
    int n_nodes)
{
    __shared__ float sW1[NFEAT * NHID];   // [k][j] 16 KB
    __shared__ float sW2[NHID * 17];      // [j][c] padded
    __shared__ float sb1[NHID];
    __shared__ float sb2[NCLASS];
    __shared__ float sh0[32][68];         // 32 nodes/block, padded rows
    __shared__ float sh1[32][68];
    __shared__ int   sIdx[8][64];

    int tid = threadIdx.x;
    for (int i = tid; i < NFEAT * NHID; i += 512) sW1[i] = W1[i];
    for (int i = tid; i < NHID * NCLASS; i += 512) sW2[(i >> 4) * 17 + (i & 15)] = W2[i];
    if (tid < NHID) sb1[tid] = b1[tid];
    if (tid < NCLASS) sb2[tid] = b2[tid];
    __syncthreads();

    float eps1 = 1.0f + eps_p[0];
    int wave = tid >> 6;
    int lane = tid & 63;
    int q = lane >> 4;        // node sub-index 0..3
    int f = lane & 15;        // staging slot 0..15 / layer2 class slot
    int s8 = (lane >> 3) & 1; // edge parity within group
    int f8 = lane & 7;        // feature octet 0..7 (16B of fp16)
    int nloc = wave * 4 + q;  // local node row

    for (int nb0 = blockIdx.x * 32; nb0 < n_nodes; nb0 += gridDim.x * 32) {
        int myNode = nb0 + nloc;
        bool valid = myNode < n_nodes;
        int s = 0, e = 0;
        if (valid) { s = row_ptr[myNode]; e = row_ptr[myNode + 1]; }
        int dmax = e - s;
        dmax = max(dmax, __shfl_xor(dmax, 16));
        dmax = max(dmax, __shfl_xor(dmax, 32));

        // accA = features f8*8..+3, accB = f8*8+4..+7 (partial over edge parity s8)
        float4 accA = make_float4(0.f, 0.f, 0.f, 0.f);
        float4 accB = make_float4(0.f, 0.f, 0.f, 0.f);
        for (int base = 0; base < dmax; base += 16) {
            int p = s + base + f;                       // lane stages slot q*16+f
            sIdx[wave][lane] = (p < e) ? csr_src[p] : -1;
            // wave-lockstep LDS write->read, no barrier
            #pragma unroll
            for (int t = 0; t < 8; ++t) {
                int idx = sIdx[wave][q * 16 + t * 2 + s8];
                if (idx >= 0) {
                    const uint4* rp = (const uint4*)(xh + (size_t)idx * 16);
                    uint4 u = rp[f8];                   // 16B = 8 fp16 features
                    __half2 h0 = *reinterpret_cast<__half2*>(&u.x);
                    __half2 h1 = *reinterpret_cast<__half2*>(&u.y);
                    __half2 h2 = *reinterpret_cast<__half2*>(&u.z);
                    __half2 h3 = *reinterpret_cast<__half2*>(&u.w);
                    float2 g0 = __half22float2(h0);
                    float2 g1 = __half22float2(h1);
                    float2 g2 = __half22float2(h2);
                    float2 g3 = __half22float2(h3);
                    accA.x += g0.x; accA.y += g0.y; accA.z += g1.x; accA.w += g1.y;
                    accB.x += g2.x; accB.y += g2.y; accB.z += g3.x; accB.w += g3.y;
                }
            }
        }
        // combine the two edge-parity partials (lane ^ 8 within 16-lane group)
        accA.x += __shfl_xor(accA.x, 8); accA.y += __shfl_xor(accA.y, 8);
        accA.z += __shfl_xor(accA.z, 8); accA.w += __shfl_xor(accA.w, 8);
        accB.x += __shfl_xor(accB.x, 8); accB.y += __shfl_xor(accB.y, 8);
        accB.z += __shfl_xor(accB.z, 8); accB.w += __shfl_xor(accB.w, 8);
        if (s8 == 0) {
            if (valid) {
                float4 xa = x4[(size_t)myNode * 16 + f8 * 2];
                float4 xb = x4[(size_t)myNode * 16 + f8 * 2 + 1];
                accA.x += eps1 * xa.x; accA.y += eps1 * xa.y;
                accA.z += eps1 * xa.z; accA.w += eps1 * xa.w;
                accB.x += eps1 * xb.x; accB.y += eps1 * xb.y;
                accB.z += eps1 * xb.z; accB.w += eps1 * xb.w;
            }
            *(float4*)&sh0[nloc][f8 * 8] = accA;
            *(float4*)&sh0[nloc][f8 * 8 + 4] = accB;
        }

        // layer1: lane j computes h1[j] for the wave's 4 nodes
        int r = wave * 4;
        float a0 = sb1[lane], a1 = a0, a2 = a0, a3 = a0;
        #pragma unroll
        for (int kk = 0; kk < 16; ++kk) {
            float4 h0 = *(const float4*)&sh0[r + 0][kk * 4];   // broadcast reads
            float4 h1v = *(const float4*)&sh0[r + 1][kk * 4];
            float4 h2 = *(const float4*)&sh0[r + 2][kk * 4];
            float4 h3 = *(const float4*)&sh0[r + 3][kk * 4];
            #pragma unroll
            for (int i = 0; i < 4; ++i) {
                float w = sW1[(kk * 4 + i) * NHID + lane];
                a0 += ((const float*)&h0)[i] * w;
                a1 += ((const float*)&h1v)[i] * w;
                a2 += ((const float*)&h2)[i] * w;
                a3 += ((const float*)&h3)[i] * w;
            }
        }
        sh1[r + 0][lane] = fmaxf(a0, 0.f);
        sh1[r + 1][lane] = fmaxf(a1, 0.f);
        sh1[r + 2][lane] = fmaxf(a2, 0.f);
        sh1[r + 3][lane] = fmaxf(a3, 0.f);

        // layer2: lane (q,f) -> out[myNode][f]
        float o = sb2[f];
        #pragma unroll
        for (int jj = 0; jj < 16; ++jj) {
            float4 hv = *(const float4*)&sh1[nloc][jj * 4];
            o += hv.x * sW2[(jj * 4 + 0) * 17 + f];
            o += hv.y * sW2[(jj * 4 + 1) * 17 + f];
            o += hv.z * sW2[(jj * 4 + 2) * 17 + f];
            o += hv.w * sW2[(jj * 4 + 3) * 17 + f];
        }
        if (valid) out[(size_t)myNode * NCLASS + f] = o;
    }
}

extern "C" void kernel_launch(void* const* d_in, const int* in_sizes, int n_in,
                              void* d_out, int out_size, void* d_ws, size_t ws_size,
                              hipStream_t stream) {
    const float* x   = (const float*)d_in[0];
    const int*   ei  = (const int*)d_in[1];
    const float* eps = (const float*)d_in[2];
    const float* W1  = (const float*)d_in[3];
    const float* b1  = (const float*)d_in[4];
    const float* W2  = (const float*)d_in[5];
    const float* b2  = (const float*)d_in[6];
    float* out = (float*)d_out;

    int n_nodes = in_sizes[0] / NFEAT;            // 100000
    int n_edges = in_sizes[1] / 2;                // 1600000
    int nbuck = (n_nodes + 255) / 256;            // 391

    char* ws = (char*)d_ws;
    int* cursor  = (int*)ws;
    int* bbase   = (int*)(ws + 2048);
    int* dsts    = (int*)(ws + 4096);
    size_t o_rp  = 4096 + (size_t)nbuck * PCAP * 4;        // dsts end
    int* row_ptr = (int*)(ws + o_rp);
    int* csr_src = (int*)(ws + o_rp + 400128);
    size_t o_xh  = o_rp + 400128 + (size_t)n_edges * 4;    // csr end
    o_xh = (o_xh + 15) & ~(size_t)15;
    uint2* xh    = (uint2*)(ws + o_xh);                    // [n][16] fp16x4, 12.8MB

    int n4 = n_nodes * 16;
    k_init<<<1, 512, 0, stream>>>(cursor, nbuck);
    k_cvt<<<(n4 + 511) / 512, 512, 0, stream>>>((const float4*)x, xh, n4);
    k_part<<<(n_edges + PT * PEPT - 1) / (PT * PEPT), PT, 0, stream>>>(
        ei, cursor, dsts, n_edges, nbuck);
    k_bscan<<<1, 512, 0, stream>>>(cursor, bbase, row_ptr, nbuck, n_edges, n_nodes);
    k_bsort<<<nbuck, ST, 0, stream>>>(dsts, cursor, bbase, csr_src, row_ptr, n_nodes);
    int ntile = (n_nodes + 31) / 32;
    int ngrid = ntile < 1024 ? ntile : 1024;      // grid-stride ~3 tiles/block
    k_gather_mlp<<<ngrid, 512, 0, stream>>>(
        (const float4*)x, xh, row_ptr, csr_src, eps, W1, b1, W2, b2, out, n_nodes);
}